// Round 7
// baseline (260.629 us; speedup 1.0000x reference)
//
#include <hip/hip_runtime.h>
#include <hip/hip_bf16.h>

#define BM_ 128   // B*M
#define T_  256
#define C_  512
#define NH  8
#define DH  64

typedef __bf16 bf16;
typedef __attribute__((ext_vector_type(8))) __bf16 bf16x8;
typedef __attribute__((ext_vector_type(4))) float f32x4;

__device__ __forceinline__ float elu1(float v){ return v > 0.f ? v + 1.f : __expf(v); }

__device__ __forceinline__ unsigned short f2bf(float f){
  unsigned u = __float_as_uint(f);
  u += 0x7fffu + ((u >> 16) & 1u);
  return (unsigned short)(u >> 16);
}

__device__ __forceinline__ float bf2f(unsigned short b){
  return __uint_as_float(((unsigned)b) << 16);
}

#define GLOAD16(gptr, lptr) __builtin_amdgcn_global_load_lds( \
  (const __attribute__((address_space(1))) void*)(gptr), \
  (__attribute__((address_space(3))) void*)(lptr), 16, 0, 0)

#define FENCE() asm volatile("" ::: "memory")

// weights fp32 -> bf16 (RNE): Wk and Wq, one launch, 65536 float4 each
__global__ __launch_bounds__(256) void wcvt_kernel(
    const float* __restrict__ wk, const float* __restrict__ wq,
    unsigned short* __restrict__ ok, unsigned short* __restrict__ oq)
{
  int i = blockIdx.x * 256 + threadIdx.x;
  float4 v = reinterpret_cast<const float4*>(wk)[i];
  ushort4 o;
  o.x = f2bf(v.x); o.y = f2bf(v.y); o.z = f2bf(v.z); o.w = f2bf(v.w);
  reinterpret_cast<ushort4*>(ok)[i] = o;
  v = reinterpret_cast<const float4*>(wq)[i];
  o.x = f2bf(v.x); o.y = f2bf(v.y); o.z = f2bf(v.z); o.w = f2bf(v.w);
  reinterpret_cast<ushort4*>(oq)[i] = o;
}

// Fused bf16 MFMA projection GEMM, 256x256 tile, BK=64, 8 waves (2M x 4N).
// LDS 128KB double-buffered, XOR-swizzled. 4 phases/K-tile of 16 MFMA w/ setprio.
// MODE 0 (K): A is reg-staged from FP32 x (fused convert); converted tile is
//             ds_written swizzled AND (tn==0) global-stored to xb for reuse by
//             xk/gemmQ. Epilogue: krow direct, ksum partials ksum2[wr][bm][d].
// MODE 1 (Q): A staged from bf16 xb via global_load_lds (pre-swizzled source).
//             Epilogue: zden = q . (ksum2[0]+ksum2[1]) direct store.
template<int MODE>
__global__ __launch_bounds__(512, 2) void gemm_proj(
    const bf16* __restrict__ A, const float* __restrict__ Axf,
    unsigned short* __restrict__ xbout,
    const bf16* __restrict__ Bw, const float* __restrict__ bias,
    float* __restrict__ krow, float* __restrict__ ksum2,
    const float* __restrict__ ksum2_in, float* __restrict__ zden)
{
  __shared__ bf16 As[2][256 * 64];
  __shared__ bf16 Bs[2][256 * 64];

  const int tid  = threadIdx.x;
  const int lane = tid & 63;
  const int wid  = tid >> 6;
  const int wr   = wid >> 2, wc = wid & 3;    // 2M x 4N wave grid

  // XCD-bijective swizzle: 256 blocks, 32 per XCD; tn fastest (A-tile L2 reuse).
  const int L  = ((blockIdx.x & 7) << 5) + (blockIdx.x >> 3);
  const int tn = L & 1, tm = L >> 1;          // tm == bm (M-tile 256 == T_)

  const bf16* Ab = A  + (size_t)(tm * 256) * C_;
  const bf16* Bb = Bw + (size_t)(tn * 256) * C_;

  const int srow  = tid >> 3;   // staging: 64 rows per call, 8 x 16B slots/row
  const int sslot = tid & 7;
  const int fr = lane & 15, fq = lane >> 4;

  f32x4 acc[8][4];
#pragma unroll
  for (int m = 0; m < 8; ++m)
#pragma unroll
    for (int n = 0; n < 4; ++n) acc[m][n] = (f32x4){0.f, 0.f, 0.f, 0.f};

  // B (and MODE1 A): global_load_lds, linear dest, pre-swizzled source.
#define STG(XS, Xb, b, h, kt) do { \
  _Pragma("unroll") \
  for (int q = 0; q < 2; ++q) { \
    int r_ = (h) * 128 + q * 64 + srow; \
    GLOAD16(Xb + (size_t)r_ * C_ + (kt) * 64 + ((sslot ^ (r_ & 7)) << 3), \
            &XS[b][(((h) * 128 + q * 64) << 6) + (tid << 3)]); \
  } } while (0)

  // LDS elem offset for (row, 16B-slot) with swizzle
#define LOFF(row, sl) (((row) << 6) + ((((sl) ^ ((row) & 7))) << 3))

  // MODE 0 A staging: issue fp32 loads into regs (compiler tracks the dep)
#define AISSUE(LO, HI, h, kt) do { \
  _Pragma("unroll") \
  for (int q = 0; q < 2; ++q) { \
    int r_ = (h) * 128 + q * 64 + srow; \
    const float* gp = Axf + (size_t)(tm * 256 + r_) * C_ + (kt) * 64 + sslot * 8; \
    LO[q] = *reinterpret_cast<const float4*>(gp); \
    HI[q] = *reinterpret_cast<const float4*>(gp + 4); \
  } } while (0)

  // MODE 0 A write: convert, swizzled ds_write, and (tn==0) store bf16 to xb
#define AWRITE(LO, HI, b, h, kt) do { \
  _Pragma("unroll") \
  for (int q = 0; q < 2; ++q) { \
    int r_ = (h) * 128 + q * 64 + srow; \
    uint4 v; \
    v.x = (unsigned)f2bf(LO[q].x) | ((unsigned)f2bf(LO[q].y) << 16); \
    v.y = (unsigned)f2bf(LO[q].z) | ((unsigned)f2bf(LO[q].w) << 16); \
    v.z = (unsigned)f2bf(HI[q].x) | ((unsigned)f2bf(HI[q].y) << 16); \
    v.w = (unsigned)f2bf(HI[q].z) | ((unsigned)f2bf(HI[q].w) << 16); \
    *reinterpret_cast<uint4*>(&As[b][LOFF(r_, sslot)]) = v; \
    if (tn == 0) \
      *reinterpret_cast<uint4*>(xbout + (size_t)(tm * 256 + r_) * C_ + (kt) * 64 + sslot * 8) = v; \
  } } while (0)

  float4 a0l[2], a0h[2], a1l[2], a1h[2];

  // prologue: stage tile 0 fully, drain, barrier
  if constexpr (MODE == 0) {
    AISSUE(a0l, a0h, 0, 0); AISSUE(a1l, a1h, 1, 0);
    STG(Bs, Bb, 0, 0, 0);   STG(Bs, Bb, 0, 1, 0);
    AWRITE(a0l, a0h, 0, 0, 0); AWRITE(a1l, a1h, 0, 1, 0);
  } else {
    STG(As, Ab, 0, 0, 0); STG(As, Ab, 0, 1, 0);
    STG(Bs, Bb, 0, 0, 0); STG(Bs, Bb, 0, 1, 0);
  }
  asm volatile("s_waitcnt vmcnt(0) lgkmcnt(0)" ::: "memory");
  __builtin_amdgcn_s_barrier();
  FENCE();

  bf16x8 af[4][2], bfr[4][2];

  for (int t = 0; t < 8; ++t) {
    const int cur = t & 1;
    const bool pre = (t < 7);
    // ---- P0: read A-half0 frags + B n0-1; issue A-h0'/stage B-h0'; MFMA m0-3 n0-1
#pragma unroll
    for (int m = 0; m < 4; ++m)
#pragma unroll
      for (int kk = 0; kk < 2; ++kk) {
        int row = wr * 128 + m * 16 + fr;
        af[m][kk] = *reinterpret_cast<const bf16x8*>(&As[cur][LOFF(row, kk * 4 + fq)]);
      }
#pragma unroll
    for (int n = 0; n < 2; ++n)
#pragma unroll
      for (int kk = 0; kk < 2; ++kk) {
        int row = wc * 64 + n * 16 + fr;
        bfr[n][kk] = *reinterpret_cast<const bf16x8*>(&Bs[cur][LOFF(row, kk * 4 + fq)]);
      }
    if (pre) {
      if constexpr (MODE == 0) AISSUE(a0l, a0h, 0, t + 1);
      else                     STG(As, Ab, cur ^ 1, 0, t + 1);
      STG(Bs, Bb, cur ^ 1, 0, t + 1);
    }
    __builtin_amdgcn_s_setprio(1);
#pragma unroll
    for (int m = 0; m < 4; ++m)
#pragma unroll
      for (int n = 0; n < 2; ++n)
#pragma unroll
        for (int kk = 0; kk < 2; ++kk)
          acc[m][n] = __builtin_amdgcn_mfma_f32_16x16x32_bf16(af[m][kk], bfr[n][kk], acc[m][n], 0, 0, 0);
    __builtin_amdgcn_s_setprio(0);
    __builtin_amdgcn_s_barrier();
    FENCE();
    // ---- P1: read B n2-3; issue A-h1'/stage B-h1'; MFMA m0-3 n2-3
#pragma unroll
    for (int n = 0; n < 2; ++n)
#pragma unroll
      for (int kk = 0; kk < 2; ++kk) {
        int row = wc * 64 + (n + 2) * 16 + fr;
        bfr[n + 2][kk] = *reinterpret_cast<const bf16x8*>(&Bs[cur][LOFF(row, kk * 4 + fq)]);
      }
    if (pre) {
      if constexpr (MODE == 0) AISSUE(a1l, a1h, 1, t + 1);
      else                     STG(As, Ab, cur ^ 1, 1, t + 1);
      STG(Bs, Bb, cur ^ 1, 1, t + 1);
    }
    __builtin_amdgcn_s_setprio(1);
#pragma unroll
    for (int m = 0; m < 4; ++m)
#pragma unroll
      for (int n = 0; n < 2; ++n)
#pragma unroll
        for (int kk = 0; kk < 2; ++kk)
          acc[m][n + 2] = __builtin_amdgcn_mfma_f32_16x16x32_bf16(af[m][kk], bfr[n + 2][kk], acc[m][n + 2], 0, 0, 0);
    __builtin_amdgcn_s_setprio(0);
    __builtin_amdgcn_s_barrier();
    FENCE();
    // ---- P2: read A-half1 frags (overwrite af); write A-h0'; MFMA m4-7 n0-1
#pragma unroll
    for (int m = 0; m < 4; ++m)
#pragma unroll
      for (int kk = 0; kk < 2; ++kk) {
        int row = wr * 128 + 64 + m * 16 + fr;
        af[m][kk] = *reinterpret_cast<const bf16x8*>(&As[cur][LOFF(row, kk * 4 + fq)]);
      }
    if (pre) { if constexpr (MODE == 0) AWRITE(a0l, a0h, cur ^ 1, 0, t + 1); }
    __builtin_amdgcn_s_setprio(1);
#pragma unroll
    for (int m = 0; m < 4; ++m)
#pragma unroll
      for (int n = 0; n < 2; ++n)
#pragma unroll
        for (int kk = 0; kk < 2; ++kk)
          acc[m + 4][n] = __builtin_amdgcn_mfma_f32_16x16x32_bf16(af[m][kk], bfr[n][kk], acc[m + 4][n], 0, 0, 0);
    __builtin_amdgcn_s_setprio(0);
    __builtin_amdgcn_s_barrier();
    FENCE();
    // ---- P3: write A-h1'; MFMA m4-7 n2-3; drain; boundary barrier
    if (pre) { if constexpr (MODE == 0) AWRITE(a1l, a1h, cur ^ 1, 1, t + 1); }
    __builtin_amdgcn_s_setprio(1);
#pragma unroll
    for (int m = 0; m < 4; ++m)
#pragma unroll
      for (int n = 0; n < 2; ++n)
#pragma unroll
        for (int kk = 0; kk < 2; ++kk)
          acc[m + 4][n + 2] = __builtin_amdgcn_mfma_f32_16x16x32_bf16(af[m][kk], bfr[n + 2][kk], acc[m + 4][n + 2], 0, 0, 0);
    __builtin_amdgcn_s_setprio(0);
    asm volatile("s_waitcnt vmcnt(0) lgkmcnt(0)" ::: "memory");
    __builtin_amdgcn_s_barrier();
    FENCE();
  }
#undef STG
#undef LOFF
#undef AISSUE
#undef AWRITE

  // ---- epilogue ----
  const int bm   = tm;
  const int head = tn * 4 + wc;
  float bj[4];
#pragma unroll
  for (int n = 0; n < 4; ++n) bj[n] = bias[tn * 256 + wc * 64 + n * 16 + fr];

  if (MODE == 0) {
    float cs[4] = {0.f, 0.f, 0.f, 0.f};
#pragma unroll
    for (int m = 0; m < 8; ++m) {
#pragma unroll
      for (int r = 0; r < 4; ++r) {
        float rs = 0.f;
#pragma unroll
        for (int n = 0; n < 4; ++n) {
          float v = elu1(acc[m][n][r] + bj[n]);
          rs += v;
          cs[n] += v;
        }
#pragma unroll
        for (int msk = 1; msk < 16; msk <<= 1) rs += __shfl_xor(rs, msk);
        if (fr == 0) {
          int tg = wr * 128 + m * 16 + fq * 4 + r;
          krow[((size_t)bm * NH + head) * T_ + tg] = rs;
        }
      }
    }
#pragma unroll
    for (int n = 0; n < 4; ++n) {
      cs[n] += __shfl_xor(cs[n], 16);
      cs[n] += __shfl_xor(cs[n], 32);
      if (fq == 0)
        ksum2[((size_t)wr * BM_ + bm) * C_ + tn * 256 + wc * 64 + n * 16 + fr] = cs[n];
    }
  } else {
    float ks[4];
#pragma unroll
    for (int n = 0; n < 4; ++n) {
      size_t col = (size_t)bm * C_ + tn * 256 + wc * 64 + n * 16 + fr;
      ks[n] = ksum2_in[col] + ksum2_in[(size_t)BM_ * C_ + col];
    }
#pragma unroll
    for (int m = 0; m < 8; ++m) {
#pragma unroll
      for (int r = 0; r < 4; ++r) {
        float zs = 0.f;
#pragma unroll
        for (int n = 0; n < 4; ++n) zs = fmaf(elu1(acc[m][n][r] + bj[n]), ks[n], zs);
#pragma unroll
        for (int msk = 1; msk < 16; msk <<= 1) zs += __shfl_xor(zs, msk);
        if (fr == 0) {
          int tg = wr * 128 + m * 16 + fq * 4 + r;
          zden[((size_t)bm * NH + head) * T_ + tg] = zs;
        }
      }
    }
  }
}

// xk4[q][bm,n,c] = sum_{t in quarter q} krow_n[t] * x[bm,t,c]; srow4 likewise.
__global__ __launch_bounds__(256) void xk_kernel(
    const unsigned short* __restrict__ xb, const float* __restrict__ krow,
    float* __restrict__ xk4, float* __restrict__ srow4)
{
  const int bm = blockIdx.x, qt = blockIdx.y, tid = threadIdx.x;
  __shared__ float krs[NH * 64];
#pragma unroll
  for (int p = 0; p < 2; ++p) {
    int idx = tid + p * 256;
    int n = idx >> 6, t = idx & 63;
    krs[idx] = krow[((size_t)bm * NH + n) * T_ + qt * 64 + t];
  }
  __syncthreads();
  float a0[8], a1[8];
#pragma unroll
  for (int n = 0; n < 8; ++n) { a0[n] = 0.f; a1[n] = 0.f; }
  const unsigned short* xp = xb + ((size_t)bm * T_ + qt * 64) * C_ + tid * 2;
  for (int t = 0; t < 64; ++t) {
    ushort2 u = *reinterpret_cast<const ushort2*>(xp + (size_t)t * C_);
    float x0 = bf2f(u.x), x1 = bf2f(u.y);
#pragma unroll
    for (int n = 0; n < 8; ++n) {
      float kr = krs[n * 64 + t];
      a0[n] = fmaf(kr, x0, a0[n]);
      a1[n] = fmaf(kr, x1, a1[n]);
    }
  }
#pragma unroll
  for (int n = 0; n < 8; ++n)
    *reinterpret_cast<float2*>(&xk4[(((size_t)qt * BM_ + bm) * NH + n) * C_ + tid * 2])
        = make_float2(a0[n], a1[n]);
  if (tid < 8) {
    float s = 0.f;
    for (int t = 0; t < 64; ++t) s += krs[tid * 64 + t];
    srow4[((size_t)qt * BM_ + bm) * NH + tid] = s;
  }
}

// Fused colsum + wbuf: per block (bm-tile of 16, head h):
//  cs[bm,e]  = Wv[h*64+e,:] . (sum_q xk4[q][bm,h,:]) + (sum_q srow4)*bv
//  wbuf[bm,h,cp] = sum_e cs[bm,e] * Wp[cp, h*64+e]
__global__ __launch_bounds__(256) void vproj_kernel(
    const float* __restrict__ xk4, const float* __restrict__ srow4,
    const float* __restrict__ Wv, const float* __restrict__ bv,
    const float* __restrict__ Wp, float* __restrict__ wbuf)
{
  const int bm0 = blockIdx.x * 16, h = blockIdx.y, tid = threadIdx.x;
  __shared__ float4 xs4[16][128];
  __shared__ float cs[16][DH];
#pragma unroll
  for (int p = 0; p < 8; ++p) {
    int idx = tid + p * 256;
    int bmr = idx >> 7, c4 = idx & 127;
    float4 s = make_float4(0.f, 0.f, 0.f, 0.f);
#pragma unroll
    for (int q = 0; q < 4; ++q) {
      float4 u = *reinterpret_cast<const float4*>(
          xk4 + (((size_t)q * BM_ + bm0 + bmr) * NH + h) * C_ + c4 * 4);
      s.x += u.x; s.y += u.y; s.z += u.z; s.w += u.w;
    }
    xs4[bmr][c4] = s;
  }
  __syncthreads();
  {
    const int e = tid & 63, g = tid >> 6;     // g uniform per wave -> LDS broadcast
    const float4* wv4 = reinterpret_cast<const float4*>(Wv + (size_t)(h * DH + e) * C_);
    float acc[4] = {0.f, 0.f, 0.f, 0.f};
#pragma unroll 4
    for (int c4 = 0; c4 < 128; ++c4) {
      float4 w = wv4[c4];
#pragma unroll
      for (int i = 0; i < 4; ++i) {
        float4 a = xs4[g * 4 + i][c4];
        acc[i] += w.x * a.x + w.y * a.y + w.z * a.z + w.w * a.w;
      }
    }
    float bve = bv[h * DH + e];
#pragma unroll
    for (int i = 0; i < 4; ++i) {
      int bm = bm0 + g * 4 + i;
      float s = 0.f;
#pragma unroll
      for (int q = 0; q < 4; ++q) s += srow4[((size_t)q * BM_ + bm) * NH + h];
      cs[g * 4 + i][e] = acc[i] + s * bve;
    }
  }
  __syncthreads();
#pragma unroll
  for (int cph = 0; cph < 2; ++cph) {
    int cp = cph * 256 + tid;
    const float4* wpr = reinterpret_cast<const float4*>(Wp + (size_t)cp * C_ + h * DH);
    float4 wp[16];
#pragma unroll
    for (int e4 = 0; e4 < 16; ++e4) wp[e4] = wpr[e4];
#pragma unroll
    for (int bmr = 0; bmr < 16; ++bmr) {
      const float* ch = cs[bmr];
      float acc = 0.f;
#pragma unroll
      for (int e4 = 0; e4 < 16; ++e4)
        acc += wp[e4].x * ch[e4 * 4] + wp[e4].y * ch[e4 * 4 + 1]
             + wp[e4].z * ch[e4 * 4 + 2] + wp[e4].w * ch[e4 * 4 + 3];
      wbuf[((size_t)(bm0 + bmr) * NH + h) * C_ + cp] = acc;
    }
  }
}

// out[bm,t,c'] = sum_n z_n[t]*w_n[c'] + bp[c'],  z = 1/(zden+eps)
__global__ __launch_bounds__(256) void out_kernel(
    const float* __restrict__ zden, const float* __restrict__ wbuf,
    const float* __restrict__ bp, float* __restrict__ out)
{
  const int bm = blockIdx.x, tt = blockIdx.y, tid = threadIdx.x;
  __shared__ float zs[NH][64];
#pragma unroll
  for (int p = 0; p < 2; ++p) {
    int idx = tid + p * 256;
    int n = idx >> 6, t = idx & 63;
    zs[n][t] = 1.f / (zden[((size_t)bm * NH + n) * T_ + tt * 64 + t] + 1e-6f);
  }
  float2 wv[8];
  const int c2 = tid * 2;
#pragma unroll
  for (int n = 0; n < 8; ++n)
    wv[n] = *reinterpret_cast<const float2*>(wbuf + ((size_t)bm * NH + n) * C_ + c2);
  float2 bpv = *reinterpret_cast<const float2*>(bp + c2);
  __syncthreads();
  float* ob = out + ((size_t)bm * T_ + tt * 64) * C_;
  for (int t = 0; t < 64; ++t) {
    float o0 = bpv.x, o1 = bpv.y;
#pragma unroll
    for (int n = 0; n < 8; ++n) { float z = zs[n][t]; o0 = fmaf(z, wv[n].x, o0); o1 = fmaf(z, wv[n].y, o1); }
    *reinterpret_cast<float2*>(ob + (size_t)t * C_ + c2) = make_float2(o0, o1);
  }
}

extern "C" void kernel_launch(void* const* d_in, const int* in_sizes, int n_in,
                              void* d_out, int out_size, void* d_ws, size_t ws_size,
                              hipStream_t stream)
{
  const float* x  = (const float*)d_in[0];
  const float* Wq = (const float*)d_in[1];
  const float* bq = (const float*)d_in[2];
  const float* Wk = (const float*)d_in[3];
  const float* bk = (const float*)d_in[4];
  const float* Wv = (const float*)d_in[5];
  const float* bv = (const float*)d_in[6];
  const float* Wp = (const float*)d_in[7];
  const float* bp = (const float*)d_in[8];
  float* out = (float*)d_out;

  float* ws    = (float*)d_ws;
  float* zden  = ws;                        // 262144 f
  float* ksum2 = zden + 262144;             // 131072 f
  float* krow  = ksum2 + 131072;            // 262144 f
  float* srow4 = krow + 262144;             // 4096 f
  float* xk4   = srow4 + 4096;              // 2097152 f
  float* wbuf  = xk4 + 2097152;             // 524288 f
  unsigned short* xb  = (unsigned short*)(wbuf + 524288);  // 16.7M bf16
  unsigned short* wkb = xb + 16777216;
  unsigned short* wqb = wkb + 262144;

  wcvt_kernel<<<256, 256, 0, stream>>>(Wk, Wq, wkb, wqb);

  gemm_proj<0><<<256, 512, 0, stream>>>(nullptr, x, xb, (const bf16*)wkb, bk,
                                        krow, ksum2, nullptr, nullptr);
  xk_kernel<<<dim3(BM_, 4), 256, 0, stream>>>(xb, krow, xk4, srow4);
  vproj_kernel<<<dim3(8, 8), 256, 0, stream>>>(xk4, srow4, Wv, bv, Wp, wbuf);
  gemm_proj<1><<<256, 512, 0, stream>>>((const bf16*)xb, nullptr, nullptr,
                                        (const bf16*)wqb, bq,
                                        nullptr, ksum2, ksum2, zden);
  out_kernel<<<dim3(BM_, 4), 256, 0, stream>>>(zden, wbuf, bp, out);
}

// Round 8
// 117.392 us; speedup vs baseline: 2.2202x; 2.2202x over previous
//
#include <hip/hip_runtime.h>
#include <hip/hip_bf16.h>

#define BM_ 128   // B*M
#define T_  256
#define C_  512
#define NH  8
#define DH  64

typedef __bf16 bf16;
typedef __attribute__((ext_vector_type(8))) __bf16 bf16x8;
typedef __attribute__((ext_vector_type(4))) float f32x4;

__device__ __forceinline__ float elu1(float v){ return v > 0.f ? v + 1.f : __expf(v); }

__device__ __forceinline__ unsigned short f2bf(float f){
  unsigned u = __float_as_uint(f);
  u += 0x7fffu + ((u >> 16) & 1u);
  return (unsigned short)(u >> 16);
}

__device__ __forceinline__ float bf2f(unsigned short b){
  return __uint_as_float(((unsigned)b) << 16);
}

#define GLOAD16(gptr, lptr) __builtin_amdgcn_global_load_lds( \
  (const __attribute__((address_space(1))) void*)(gptr), \
  (__attribute__((address_space(3))) void*)(lptr), 16, 0, 0)

#define FENCE() asm volatile("" ::: "memory")

// weights fp32 -> bf16 (RNE): Wk and Wq, one launch
__global__ __launch_bounds__(256) void wcvt_kernel(
    const float* __restrict__ wk, const float* __restrict__ wq,
    unsigned short* __restrict__ ok, unsigned short* __restrict__ oq)
{
  int i = blockIdx.x * 256 + threadIdx.x;
  float4 v = reinterpret_cast<const float4*>(wk)[i];
  ushort4 o;
  o.x = f2bf(v.x); o.y = f2bf(v.y); o.z = f2bf(v.z); o.w = f2bf(v.w);
  reinterpret_cast<ushort4*>(ok)[i] = o;
  v = reinterpret_cast<const float4*>(wq)[i];
  o.x = f2bf(v.x); o.y = f2bf(v.y); o.z = f2bf(v.z); o.w = f2bf(v.w);
  reinterpret_cast<ushort4*>(oq)[i] = o;
}

// Fused bf16 MFMA projection GEMM, 256x256 tile, BK=64, 8 waves (2M x 4N).
// LDS 128KB double-buffered, XOR-swizzled. 4 phases/K-tile of 16 MFMA w/ setprio.
// MODE 0 (K): A reg-staged from FP32 x (fused convert); converted tile also
//             (tn==0) global-stored to xb for xk/gemmQ reuse.
// MODE 1 (Q): A staged from bf16 xb via global_load_lds (pre-swizzled source).
template<int MODE>
__global__ __launch_bounds__(512, 2) void gemm_proj(
    const bf16* __restrict__ A, const float* __restrict__ Axf,
    unsigned short* __restrict__ xbout,
    const bf16* __restrict__ Bw, const float* __restrict__ bias,
    float* __restrict__ krow, float* __restrict__ ksum2,
    const float* __restrict__ ksum2_in, float* __restrict__ zden)
{
  __shared__ bf16 As[2][256 * 64];
  __shared__ bf16 Bs[2][256 * 64];

  const int tid  = threadIdx.x;
  const int lane = tid & 63;
  const int wid  = tid >> 6;
  const int wr   = wid >> 2, wc = wid & 3;    // 2M x 4N wave grid

  const int L  = ((blockIdx.x & 7) << 5) + (blockIdx.x >> 3);
  const int tn = L & 1, tm = L >> 1;          // tm == bm

  const bf16* Ab = A  + (size_t)(tm * 256) * C_;
  const bf16* Bb = Bw + (size_t)(tn * 256) * C_;

  const int srow  = tid >> 3;
  const int sslot = tid & 7;
  const int fr = lane & 15, fq = lane >> 4;

  f32x4 acc[8][4];
#pragma unroll
  for (int m = 0; m < 8; ++m)
#pragma unroll
    for (int n = 0; n < 4; ++n) acc[m][n] = (f32x4){0.f, 0.f, 0.f, 0.f};

#define STG(XS, Xb, b, h, kt) do { \
  _Pragma("unroll") \
  for (int q = 0; q < 2; ++q) { \
    int r_ = (h) * 128 + q * 64 + srow; \
    GLOAD16(Xb + (size_t)r_ * C_ + (kt) * 64 + ((sslot ^ (r_ & 7)) << 3), \
            &XS[b][(((h) * 128 + q * 64) << 6) + (tid << 3)]); \
  } } while (0)

#define LOFF(row, sl) (((row) << 6) + ((((sl) ^ ((row) & 7))) << 3))

#define AISSUE(LO, HI, h, kt) do { \
  _Pragma("unroll") \
  for (int q = 0; q < 2; ++q) { \
    int r_ = (h) * 128 + q * 64 + srow; \
    const float* gp = Axf + (size_t)(tm * 256 + r_) * C_ + (kt) * 64 + sslot * 8; \
    LO[q] = *reinterpret_cast<const float4*>(gp); \
    HI[q] = *reinterpret_cast<const float4*>(gp + 4); \
  } } while (0)

#define AWRITE(LO, HI, b, h, kt) do { \
  _Pragma("unroll") \
  for (int q = 0; q < 2; ++q) { \
    int r_ = (h) * 128 + q * 64 + srow; \
    uint4 v; \
    v.x = (unsigned)f2bf(LO[q].x) | ((unsigned)f2bf(LO[q].y) << 16); \
    v.y = (unsigned)f2bf(LO[q].z) | ((unsigned)f2bf(LO[q].w) << 16); \
    v.z = (unsigned)f2bf(HI[q].x) | ((unsigned)f2bf(HI[q].y) << 16); \
    v.w = (unsigned)f2bf(HI[q].z) | ((unsigned)f2bf(HI[q].w) << 16); \
    *reinterpret_cast<uint4*>(&As[b][LOFF(r_, sslot)]) = v; \
    if (tn == 0) \
      *reinterpret_cast<uint4*>(xbout + (size_t)(tm * 256 + r_) * C_ + (kt) * 64 + sslot * 8) = v; \
  } } while (0)

  float4 a0l[2], a0h[2], a1l[2], a1h[2];

  if constexpr (MODE == 0) {
    AISSUE(a0l, a0h, 0, 0); AISSUE(a1l, a1h, 1, 0);
    STG(Bs, Bb, 0, 0, 0);   STG(Bs, Bb, 0, 1, 0);
    AWRITE(a0l, a0h, 0, 0, 0); AWRITE(a1l, a1h, 0, 1, 0);
  } else {
    STG(As, Ab, 0, 0, 0); STG(As, Ab, 0, 1, 0);
    STG(Bs, Bb, 0, 0, 0); STG(Bs, Bb, 0, 1, 0);
  }
  asm volatile("s_waitcnt vmcnt(0) lgkmcnt(0)" ::: "memory");
  __builtin_amdgcn_s_barrier();
  FENCE();

  bf16x8 af[4][2], bfr[4][2];

  for (int t = 0; t < 8; ++t) {
    const int cur = t & 1;
    const bool pre = (t < 7);
    // P0
#pragma unroll
    for (int m = 0; m < 4; ++m)
#pragma unroll
      for (int kk = 0; kk < 2; ++kk) {
        int row = wr * 128 + m * 16 + fr;
        af[m][kk] = *reinterpret_cast<const bf16x8*>(&As[cur][LOFF(row, kk * 4 + fq)]);
      }
#pragma unroll
    for (int n = 0; n < 2; ++n)
#pragma unroll
      for (int kk = 0; kk < 2; ++kk) {
        int row = wc * 64 + n * 16 + fr;
        bfr[n][kk] = *reinterpret_cast<const bf16x8*>(&Bs[cur][LOFF(row, kk * 4 + fq)]);
      }
    if (pre) {
      if constexpr (MODE == 0) AISSUE(a0l, a0h, 0, t + 1);
      else                     STG(As, Ab, cur ^ 1, 0, t + 1);
      STG(Bs, Bb, cur ^ 1, 0, t + 1);
    }
    __builtin_amdgcn_s_setprio(1);
#pragma unroll
    for (int m = 0; m < 4; ++m)
#pragma unroll
      for (int n = 0; n < 2; ++n)
#pragma unroll
        for (int kk = 0; kk < 2; ++kk)
          acc[m][n] = __builtin_amdgcn_mfma_f32_16x16x32_bf16(af[m][kk], bfr[n][kk], acc[m][n], 0, 0, 0);
    __builtin_amdgcn_s_setprio(0);
    __builtin_amdgcn_s_barrier();
    FENCE();
    // P1
#pragma unroll
    for (int n = 0; n < 2; ++n)
#pragma unroll
      for (int kk = 0; kk < 2; ++kk) {
        int row = wc * 64 + (n + 2) * 16 + fr;
        bfr[n + 2][kk] = *reinterpret_cast<const bf16x8*>(&Bs[cur][LOFF(row, kk * 4 + fq)]);
      }
    if (pre) {
      if constexpr (MODE == 0) AISSUE(a1l, a1h, 1, t + 1);
      else                     STG(As, Ab, cur ^ 1, 1, t + 1);
      STG(Bs, Bb, cur ^ 1, 1, t + 1);
    }
    __builtin_amdgcn_s_setprio(1);
#pragma unroll
    for (int m = 0; m < 4; ++m)
#pragma unroll
      for (int n = 0; n < 2; ++n)
#pragma unroll
        for (int kk = 0; kk < 2; ++kk)
          acc[m][n + 2] = __builtin_amdgcn_mfma_f32_16x16x32_bf16(af[m][kk], bfr[n + 2][kk], acc[m][n + 2], 0, 0, 0);
    __builtin_amdgcn_s_setprio(0);
    __builtin_amdgcn_s_barrier();
    FENCE();
    // P2
#pragma unroll
    for (int m = 0; m < 4; ++m)
#pragma unroll
      for (int kk = 0; kk < 2; ++kk) {
        int row = wr * 128 + 64 + m * 16 + fr;
        af[m][kk] = *reinterpret_cast<const bf16x8*>(&As[cur][LOFF(row, kk * 4 + fq)]);
      }
    if (pre) { if constexpr (MODE == 0) AWRITE(a0l, a0h, cur ^ 1, 0, t + 1); }
    __builtin_amdgcn_s_setprio(1);
#pragma unroll
    for (int m = 0; m < 4; ++m)
#pragma unroll
      for (int n = 0; n < 2; ++n)
#pragma unroll
        for (int kk = 0; kk < 2; ++kk)
          acc[m + 4][n] = __builtin_amdgcn_mfma_f32_16x16x32_bf16(af[m][kk], bfr[n][kk], acc[m + 4][n], 0, 0, 0);
    __builtin_amdgcn_s_setprio(0);
    __builtin_amdgcn_s_barrier();
    FENCE();
    // P3
    if (pre) { if constexpr (MODE == 0) AWRITE(a1l, a1h, cur ^ 1, 1, t + 1); }
    __builtin_amdgcn_s_setprio(1);
#pragma unroll
    for (int m = 0; m < 4; ++m)
#pragma unroll
      for (int n = 0; n < 2; ++n)
#pragma unroll
        for (int kk = 0; kk < 2; ++kk)
          acc[m + 4][n + 2] = __builtin_amdgcn_mfma_f32_16x16x32_bf16(af[m][kk], bfr[n + 2][kk], acc[m + 4][n + 2], 0, 0, 0);
    __builtin_amdgcn_s_setprio(0);
    asm volatile("s_waitcnt vmcnt(0) lgkmcnt(0)" ::: "memory");
    __builtin_amdgcn_s_barrier();
    FENCE();
  }
#undef STG
#undef LOFF
#undef AISSUE
#undef AWRITE

  // ---- epilogue ----
  const int bm   = tm;
  const int head = tn * 4 + wc;
  float bj[4];
#pragma unroll
  for (int n = 0; n < 4; ++n) bj[n] = bias[tn * 256 + wc * 64 + n * 16 + fr];

  if (MODE == 0) {
    float cs[4] = {0.f, 0.f, 0.f, 0.f};
#pragma unroll
    for (int m = 0; m < 8; ++m) {
#pragma unroll
      for (int r = 0; r < 4; ++r) {
        float rs = 0.f;
#pragma unroll
        for (int n = 0; n < 4; ++n) {
          float v = elu1(acc[m][n][r] + bj[n]);
          rs += v;
          cs[n] += v;
        }
#pragma unroll
        for (int msk = 1; msk < 16; msk <<= 1) rs += __shfl_xor(rs, msk);
        if (fr == 0) {
          int tg = wr * 128 + m * 16 + fq * 4 + r;
          krow[((size_t)bm * NH + head) * T_ + tg] = rs;
        }
      }
    }
#pragma unroll
    for (int n = 0; n < 4; ++n) {
      cs[n] += __shfl_xor(cs[n], 16);
      cs[n] += __shfl_xor(cs[n], 32);
      if (fq == 0)
        ksum2[((size_t)wr * BM_ + bm) * C_ + tn * 256 + wc * 64 + n * 16 + fr] = cs[n];
    }
  } else {
    float ks[4];
#pragma unroll
    for (int n = 0; n < 4; ++n) {
      size_t col = (size_t)bm * C_ + tn * 256 + wc * 64 + n * 16 + fr;
      ks[n] = ksum2_in[col] + ksum2_in[(size_t)BM_ * C_ + col];
    }
#pragma unroll
    for (int m = 0; m < 8; ++m) {
#pragma unroll
      for (int r = 0; r < 4; ++r) {
        float zs = 0.f;
#pragma unroll
        for (int n = 0; n < 4; ++n) zs = fmaf(elu1(acc[m][n][r] + bj[n]), ks[n], zs);
#pragma unroll
        for (int msk = 1; msk < 16; msk <<= 1) zs += __shfl_xor(zs, msk);
        if (fr == 0) {
          int tg = wr * 128 + m * 16 + fq * 4 + r;
          zden[((size_t)bm * NH + head) * T_ + tg] = zs;
        }
      }
    }
  }
}

// xk4[q][bm,n,c] = sum_{t in quarter q} krow_n[t] * x[bm,t,c]; srow4 likewise.
__global__ __launch_bounds__(256) void xk_kernel(
    const unsigned short* __restrict__ xb, const float* __restrict__ krow,
    float* __restrict__ xk4, float* __restrict__ srow4)
{
  const int bm = blockIdx.x, qt = blockIdx.y, tid = threadIdx.x;
  __shared__ float krs[NH * 64];
#pragma unroll
  for (int p = 0; p < 2; ++p) {
    int idx = tid + p * 256;
    int n = idx >> 6, t = idx & 63;
    krs[idx] = krow[((size_t)bm * NH + n) * T_ + qt * 64 + t];
  }
  __syncthreads();
  float a0[8], a1[8];
#pragma unroll
  for (int n = 0; n < 8; ++n) { a0[n] = 0.f; a1[n] = 0.f; }
  const unsigned short* xp = xb + ((size_t)bm * T_ + qt * 64) * C_ + tid * 2;
  for (int t = 0; t < 64; ++t) {
    ushort2 u = *reinterpret_cast<const ushort2*>(xp + (size_t)t * C_);
    float x0 = bf2f(u.x), x1 = bf2f(u.y);
#pragma unroll
    for (int n = 0; n < 8; ++n) {
      float kr = krs[n * 64 + t];
      a0[n] = fmaf(kr, x0, a0[n]);
      a1[n] = fmaf(kr, x1, a1[n]);
    }
  }
#pragma unroll
  for (int n = 0; n < 8; ++n)
    *reinterpret_cast<float2*>(&xk4[(((size_t)qt * BM_ + bm) * NH + n) * C_ + tid * 2])
        = make_float2(a0[n], a1[n]);
  if (tid < 8) {
    float s = 0.f;
    for (int t = 0; t < 64; ++t) s += krs[tid * 64 + t];
    srow4[((size_t)qt * BM_ + bm) * NH + tid] = s;
  }
}

// colsum[bm,h,e] = Wv[h*64+e,:] . (sum_q xk4) + (sum_q srow4)*bv[h*64+e]
__global__ __launch_bounds__(256) void colsum_kernel(
    const float* __restrict__ xk4, const float* __restrict__ srow4,
    const float* __restrict__ Wv, const float* __restrict__ bv,
    float* __restrict__ cs_g)
{
  const int bm0 = blockIdx.x * 8, h = blockIdx.y, tid = threadIdx.x;
  __shared__ float4 xs4[8][128];
#pragma unroll
  for (int p = 0; p < 4; ++p) {
    int idx = tid + p * 256;
    int bmr = idx >> 7, c4 = idx & 127;
    float4 s = make_float4(0.f, 0.f, 0.f, 0.f);
#pragma unroll
    for (int q = 0; q < 4; ++q) {
      float4 u = *reinterpret_cast<const float4*>(
          xk4 + (((size_t)q * BM_ + bm0 + bmr) * NH + h) * C_ + c4 * 4);
      s.x += u.x; s.y += u.y; s.z += u.z; s.w += u.w;
    }
    xs4[bmr][c4] = s;
  }
  __syncthreads();
  const int e = tid & 63, bs = tid >> 6;
  const float4* wv4 = reinterpret_cast<const float4*>(Wv + (size_t)(h * DH + e) * C_);
  float acc0 = 0.f, acc1 = 0.f;
#pragma unroll 4
  for (int c4 = 0; c4 < 128; ++c4) {
    float4 w = wv4[c4];
    float4 a = xs4[bs * 2][c4];
    float4 b = xs4[bs * 2 + 1][c4];
    acc0 += w.x * a.x + w.y * a.y + w.z * a.z + w.w * a.w;
    acc1 += w.x * b.x + w.y * b.y + w.z * b.z + w.w * b.w;
  }
  float bve = bv[h * DH + e];
  int bmA = bm0 + bs * 2, bmB = bmA + 1;
  float sA = 0.f, sB = 0.f;
#pragma unroll
  for (int q = 0; q < 4; ++q) {
    sA += srow4[((size_t)q * BM_ + bmA) * NH + h];
    sB += srow4[((size_t)q * BM_ + bmB) * NH + h];
  }
  cs_g[((size_t)bmA * NH + h) * DH + e] = acc0 + sA * bve;
  cs_g[((size_t)bmB * NH + h) * DH + e] = acc1 + sB * bve;
}

// wbuf[bm,h,cp] = sum_e cs[bm,h,e] * Wp[cp, h*64+e]
__global__ __launch_bounds__(256) void wbuf_kernel(
    const float* __restrict__ cs_g, const float* __restrict__ Wp,
    float* __restrict__ wbuf)
{
  const int cpt = blockIdx.x, h = blockIdx.y, bm0 = blockIdx.z * 16;
  const int tid = threadIdx.x;
  __shared__ float4 csL4[16][16];
  {
    int bmr = tid >> 4, e4 = tid & 15;
    csL4[bmr][e4] = *reinterpret_cast<const float4*>(
        cs_g + ((size_t)(bm0 + bmr) * NH + h) * DH + e4 * 4);
  }
  __syncthreads();
  const int cp = cpt * 256 + tid;
  float4 wp[16];
  const float4* wpr = reinterpret_cast<const float4*>(Wp + (size_t)cp * C_ + h * DH);
#pragma unroll
  for (int e4 = 0; e4 < 16; ++e4) wp[e4] = wpr[e4];
#pragma unroll
  for (int bmr = 0; bmr < 16; ++bmr) {
    float acc = 0.f;
#pragma unroll
    for (int e4 = 0; e4 < 16; ++e4) {
      float4 c = csL4[bmr][e4];
      acc += wp[e4].x * c.x + wp[e4].y * c.y + wp[e4].z * c.z + wp[e4].w * c.w;
    }
    wbuf[((size_t)(bm0 + bmr) * NH + h) * C_ + cp] = acc;
  }
}

// out[bm,t,c'] = sum_n z_n[t]*w_n[c'] + bp[c'],  z = 1/(zden+eps)
__global__ __launch_bounds__(256) void out_kernel(
    const float* __restrict__ zden, const float* __restrict__ wbuf,
    const float* __restrict__ bp, float* __restrict__ out)
{
  const int bm = blockIdx.x, tt = blockIdx.y, tid = threadIdx.x;
  __shared__ float zs[NH][64];
#pragma unroll
  for (int p = 0; p < 2; ++p) {
    int idx = tid + p * 256;
    int n = idx >> 6, t = idx & 63;
    zs[n][t] = 1.f / (zden[((size_t)bm * NH + n) * T_ + tt * 64 + t] + 1e-6f);
  }
  float2 wv[8];
  const int c2 = tid * 2;
#pragma unroll
  for (int n = 0; n < 8; ++n)
    wv[n] = *reinterpret_cast<const float2*>(wbuf + ((size_t)bm * NH + n) * C_ + c2);
  float2 bpv = *reinterpret_cast<const float2*>(bp + c2);
  __syncthreads();
  float* ob = out + ((size_t)bm * T_ + tt * 64) * C_;
  for (int t = 0; t < 64; ++t) {
    float o0 = bpv.x, o1 = bpv.y;
#pragma unroll
    for (int n = 0; n < 8; ++n) { float z = zs[n][t]; o0 = fmaf(z, wv[n].x, o0); o1 = fmaf(z, wv[n].y, o1); }
    *reinterpret_cast<float2*>(ob + (size_t)t * C_ + c2) = make_float2(o0, o1);
  }
}

extern "C" void kernel_launch(void* const* d_in, const int* in_sizes, int n_in,
                              void* d_out, int out_size, void* d_ws, size_t ws_size,
                              hipStream_t stream)
{
  const float* x  = (const float*)d_in[0];
  const float* Wq = (const float*)d_in[1];
  const float* bq = (const float*)d_in[2];
  const float* Wk = (const float*)d_in[3];
  const float* bk = (const float*)d_in[4];
  const float* Wv = (const float*)d_in[5];
  const float* bv = (const float*)d_in[6];
  const float* Wp = (const float*)d_in[7];
  const float* bp = (const float*)d_in[8];
  float* out = (float*)d_out;

  float* ws    = (float*)d_ws;
  float* zden  = ws;                        // 262144 f
  float* ksum2 = zden + 262144;             // 131072 f
  float* krow  = ksum2 + 131072;            // 262144 f
  float* srow4 = krow + 262144;             // 4096 f
  float* xk4   = srow4 + 4096;              // 2097152 f
  float* cs    = xk4 + 2097152;             // 65536 f
  float* wbuf  = cs + 65536;                // 524288 f
  unsigned short* xb  = (unsigned short*)(wbuf + 524288);  // 16.7M bf16
  unsigned short* wkb = xb + 16777216;
  unsigned short* wqb = wkb + 262144;

  wcvt_kernel<<<256, 256, 0, stream>>>(Wk, Wq, wkb, wqb);

  gemm_proj<0><<<256, 512, 0, stream>>>(nullptr, x, xb, (const bf16*)wkb, bk,
                                        krow, ksum2, nullptr, nullptr);
  xk_kernel<<<dim3(BM_, 4), 256, 0, stream>>>(xb, krow, xk4, srow4);
  colsum_kernel<<<dim3(16, 8), 256, 0, stream>>>(xk4, srow4, Wv, bv, cs);
  wbuf_kernel<<<dim3(2, 8, 8), 256, 0, stream>>>(cs, Wp, wbuf);
  gemm_proj<1><<<256, 512, 0, stream>>>((const bf16*)xb, nullptr, nullptr,
                                        (const bf16*)wqb, bq,
                                        nullptr, ksum2, ksum2, zden);
  out_kernel<<<dim3(BM_, 4), 256, 0, stream>>>(zden, wbuf, bp, out);
}

// Round 9
// 114.513 us; speedup vs baseline: 2.2760x; 1.0251x over previous
//
#include <hip/hip_runtime.h>
#include <hip/hip_bf16.h>

#define BM_ 128   // B*M
#define T_  256
#define C_  512
#define NH  8
#define DH  64

typedef __bf16 bf16;
typedef __attribute__((ext_vector_type(8))) __bf16 bf16x8;
typedef __attribute__((ext_vector_type(4))) float f32x4;

__device__ __forceinline__ float elu1(float v){ return v > 0.f ? v + 1.f : __expf(v); }

__device__ __forceinline__ unsigned short f2bf(float f){
  unsigned u = __float_as_uint(f);
  u += 0x7fffu + ((u >> 16) & 1u);
  return (unsigned short)(u >> 16);
}

__device__ __forceinline__ float bf2f(unsigned short b){
  return __uint_as_float(((unsigned)b) << 16);
}

// HW packed f32->bf16 (RNE on gfx950): 1 inst per 2 floats
__device__ __forceinline__ unsigned cvtpk(float lo, float hi){
  unsigned r;
  asm("v_cvt_pk_bf16_f32 %0, %1, %2" : "=v"(r) : "v"(lo), "v"(hi));
  return r;
}

#define GLOAD16(gptr, lptr) __builtin_amdgcn_global_load_lds( \
  (const __attribute__((address_space(1))) void*)(gptr), \
  (__attribute__((address_space(3))) void*)(lptr), 16, 0, 0)

#define FENCE() asm volatile("" ::: "memory")

// weights fp32 -> bf16 (RNE): Wk and Wq, one launch
__global__ __launch_bounds__(256) void wcvt_kernel(
    const float* __restrict__ wk, const float* __restrict__ wq,
    unsigned short* __restrict__ ok, unsigned short* __restrict__ oq)
{
  int i = blockIdx.x * 256 + threadIdx.x;
  float4 v = reinterpret_cast<const float4*>(wk)[i];
  ushort4 o;
  o.x = f2bf(v.x); o.y = f2bf(v.y); o.z = f2bf(v.z); o.w = f2bf(v.w);
  reinterpret_cast<ushort4*>(ok)[i] = o;
  v = reinterpret_cast<const float4*>(wq)[i];
  o.x = f2bf(v.x); o.y = f2bf(v.y); o.z = f2bf(v.z); o.w = f2bf(v.w);
  reinterpret_cast<ushort4*>(oq)[i] = o;
}

// Fused bf16 MFMA projection GEMM, 256x256 tile, BK=64, 8 waves (2M x 4N).
// LDS 128KB double-buffered, XOR-swizzled. 4 phases/K-tile of 16 MFMA w/ setprio.
// MODE 0 (K): A reg-staged from FP32 x, HW cvt_pk to bf16, ds_write AFTER the
//   phase's MFMA cluster; (tn==0) also global-stores xb. Tile boundary uses
//   vmcnt(4) for tn==0 (xb stores float across tiles; in-order retirement
//   guarantees the older B global_load_lds have landed) / vmcnt(0) for tn==1.
// MODE 1 (Q): A staged from bf16 xb via global_load_lds (pre-swizzled source).
template<int MODE>
__global__ __launch_bounds__(512, 2) void gemm_proj(
    const bf16* __restrict__ A, const float* __restrict__ Axf,
    unsigned short* __restrict__ xbout,
    const bf16* __restrict__ Bw, const float* __restrict__ bias,
    float* __restrict__ krow, float* __restrict__ ksum2,
    const float* __restrict__ ksum2_in, float* __restrict__ zden)
{
  __shared__ bf16 As[2][256 * 64];
  __shared__ bf16 Bs[2][256 * 64];

  const int tid  = threadIdx.x;
  const int lane = tid & 63;
  const int wid  = tid >> 6;
  const int wr   = wid >> 2, wc = wid & 3;    // 2M x 4N wave grid

  const int L  = ((blockIdx.x & 7) << 5) + (blockIdx.x >> 3);
  const int tn = L & 1, tm = L >> 1;          // tm == bm

  const bf16* Ab = A  + (size_t)(tm * 256) * C_;
  const bf16* Bb = Bw + (size_t)(tn * 256) * C_;

  const int srow  = tid >> 3;
  const int sslot = tid & 7;
  const int fr = lane & 15, fq = lane >> 4;

  f32x4 acc[8][4];
#pragma unroll
  for (int m = 0; m < 8; ++m)
#pragma unroll
    for (int n = 0; n < 4; ++n) acc[m][n] = (f32x4){0.f, 0.f, 0.f, 0.f};

#define STG(XS, Xb, b, h, kt) do { \
  _Pragma("unroll") \
  for (int q = 0; q < 2; ++q) { \
    int r_ = (h) * 128 + q * 64 + srow; \
    GLOAD16(Xb + (size_t)r_ * C_ + (kt) * 64 + ((sslot ^ (r_ & 7)) << 3), \
            &XS[b][(((h) * 128 + q * 64) << 6) + (tid << 3)]); \
  } } while (0)

#define LOFF(row, sl) (((row) << 6) + ((((sl) ^ ((row) & 7))) << 3))

#define AISSUE(LO, HI, h, kt) do { \
  _Pragma("unroll") \
  for (int q = 0; q < 2; ++q) { \
    int r_ = (h) * 128 + q * 64 + srow; \
    const float* gp = Axf + (size_t)(tm * 256 + r_) * C_ + (kt) * 64 + sslot * 8; \
    LO[q] = *reinterpret_cast<const float4*>(gp); \
    HI[q] = *reinterpret_cast<const float4*>(gp + 4); \
  } } while (0)

#define AWRITE(LO, HI, b, h, kt) do { \
  _Pragma("unroll") \
  for (int q = 0; q < 2; ++q) { \
    int r_ = (h) * 128 + q * 64 + srow; \
    uint4 v; \
    v.x = cvtpk(LO[q].x, LO[q].y); \
    v.y = cvtpk(LO[q].z, LO[q].w); \
    v.z = cvtpk(HI[q].x, HI[q].y); \
    v.w = cvtpk(HI[q].z, HI[q].w); \
    *reinterpret_cast<uint4*>(&As[b][LOFF(r_, sslot)]) = v; \
    if (tn == 0) \
      *reinterpret_cast<uint4*>(xbout + (size_t)(tm * 256 + r_) * C_ + (kt) * 64 + sslot * 8) = v; \
  } } while (0)

  float4 a0l[2], a0h[2], a1l[2], a1h[2];

  if constexpr (MODE == 0) {
    AISSUE(a0l, a0h, 0, 0); AISSUE(a1l, a1h, 1, 0);
    STG(Bs, Bb, 0, 0, 0);   STG(Bs, Bb, 0, 1, 0);
    AWRITE(a0l, a0h, 0, 0, 0); AWRITE(a1l, a1h, 0, 1, 0);
  } else {
    STG(As, Ab, 0, 0, 0); STG(As, Ab, 0, 1, 0);
    STG(Bs, Bb, 0, 0, 0); STG(Bs, Bb, 0, 1, 0);
  }
  asm volatile("s_waitcnt vmcnt(0) lgkmcnt(0)" ::: "memory");
  __builtin_amdgcn_s_barrier();
  FENCE();

  bf16x8 af[4][2], bfr[4][2];

  for (int t = 0; t < 8; ++t) {
    const int cur = t & 1;
    const bool pre = (t < 7);
    // P0: read A-h0 frags + B n0-1; issue A-h0' loads / stage B-h0'; MFMA m0-3 n0-1
#pragma unroll
    for (int m = 0; m < 4; ++m)
#pragma unroll
      for (int kk = 0; kk < 2; ++kk) {
        int row = wr * 128 + m * 16 + fr;
        af[m][kk] = *reinterpret_cast<const bf16x8*>(&As[cur][LOFF(row, kk * 4 + fq)]);
      }
#pragma unroll
    for (int n = 0; n < 2; ++n)
#pragma unroll
      for (int kk = 0; kk < 2; ++kk) {
        int row = wc * 64 + n * 16 + fr;
        bfr[n][kk] = *reinterpret_cast<const bf16x8*>(&Bs[cur][LOFF(row, kk * 4 + fq)]);
      }
    if (pre) {
      if constexpr (MODE == 0) AISSUE(a0l, a0h, 0, t + 1);
      else                     STG(As, Ab, cur ^ 1, 0, t + 1);
      STG(Bs, Bb, cur ^ 1, 0, t + 1);
    }
    __builtin_amdgcn_s_setprio(1);
#pragma unroll
    for (int m = 0; m < 4; ++m)
#pragma unroll
      for (int n = 0; n < 2; ++n)
#pragma unroll
        for (int kk = 0; kk < 2; ++kk)
          acc[m][n] = __builtin_amdgcn_mfma_f32_16x16x32_bf16(af[m][kk], bfr[n][kk], acc[m][n], 0, 0, 0);
    __builtin_amdgcn_s_setprio(0);
    __builtin_amdgcn_s_barrier();
    FENCE();
    // P1: read B n2-3; issue A-h1' loads / stage B-h1'; MFMA m0-3 n2-3
#pragma unroll
    for (int n = 0; n < 2; ++n)
#pragma unroll
      for (int kk = 0; kk < 2; ++kk) {
        int row = wc * 64 + (n + 2) * 16 + fr;
        bfr[n + 2][kk] = *reinterpret_cast<const bf16x8*>(&Bs[cur][LOFF(row, kk * 4 + fq)]);
      }
    if (pre) {
      if constexpr (MODE == 0) AISSUE(a1l, a1h, 1, t + 1);
      else                     STG(As, Ab, cur ^ 1, 1, t + 1);
      STG(Bs, Bb, cur ^ 1, 1, t + 1);
    }
    __builtin_amdgcn_s_setprio(1);
#pragma unroll
    for (int m = 0; m < 4; ++m)
#pragma unroll
      for (int n = 0; n < 2; ++n)
#pragma unroll
        for (int kk = 0; kk < 2; ++kk)
          acc[m][n + 2] = __builtin_amdgcn_mfma_f32_16x16x32_bf16(af[m][kk], bfr[n + 2][kk], acc[m][n + 2], 0, 0, 0);
    __builtin_amdgcn_s_setprio(0);
    __builtin_amdgcn_s_barrier();
    FENCE();
    // P2: read A-h1 frags; MFMA m4-7 n0-1; THEN cvt+write A-h0' (latency covered)
#pragma unroll
    for (int m = 0; m < 4; ++m)
#pragma unroll
      for (int kk = 0; kk < 2; ++kk) {
        int row = wr * 128 + 64 + m * 16 + fr;
        af[m][kk] = *reinterpret_cast<const bf16x8*>(&As[cur][LOFF(row, kk * 4 + fq)]);
      }
    __builtin_amdgcn_s_setprio(1);
#pragma unroll
    for (int m = 0; m < 4; ++m)
#pragma unroll
      for (int n = 0; n < 2; ++n)
#pragma unroll
        for (int kk = 0; kk < 2; ++kk)
          acc[m + 4][n] = __builtin_amdgcn_mfma_f32_16x16x32_bf16(af[m][kk], bfr[n][kk], acc[m + 4][n], 0, 0, 0);
    __builtin_amdgcn_s_setprio(0);
    if (pre) { if constexpr (MODE == 0) AWRITE(a0l, a0h, cur ^ 1, 0, t + 1); }
    __builtin_amdgcn_s_barrier();
    FENCE();
    // P3: MFMA m4-7 n2-3; THEN cvt+write A-h1'; counted boundary drain
    __builtin_amdgcn_s_setprio(1);
#pragma unroll
    for (int m = 0; m < 4; ++m)
#pragma unroll
      for (int n = 0; n < 2; ++n)
#pragma unroll
        for (int kk = 0; kk < 2; ++kk)
          acc[m + 4][n + 2] = __builtin_amdgcn_mfma_f32_16x16x32_bf16(af[m][kk], bfr[n + 2][kk], acc[m + 4][n + 2], 0, 0, 0);
    __builtin_amdgcn_s_setprio(0);
    if (pre) { if constexpr (MODE == 0) AWRITE(a1l, a1h, cur ^ 1, 1, t + 1); }
    if constexpr (MODE == 0) {
      if (tn == 0) asm volatile("s_waitcnt vmcnt(4) lgkmcnt(0)" ::: "memory");
      else         asm volatile("s_waitcnt vmcnt(0) lgkmcnt(0)" ::: "memory");
    } else {
      asm volatile("s_waitcnt vmcnt(0) lgkmcnt(0)" ::: "memory");
    }
    __builtin_amdgcn_s_barrier();
    FENCE();
  }
#undef STG
#undef LOFF
#undef AISSUE
#undef AWRITE

  // ---- epilogue ----
  const int bm   = tm;
  const int head = tn * 4 + wc;
  float bj[4];
#pragma unroll
  for (int n = 0; n < 4; ++n) bj[n] = bias[tn * 256 + wc * 64 + n * 16 + fr];

  if (MODE == 0) {
    float cs[4] = {0.f, 0.f, 0.f, 0.f};
#pragma unroll
    for (int m = 0; m < 8; ++m) {
#pragma unroll
      for (int r = 0; r < 4; ++r) {
        float rs = 0.f;
#pragma unroll
        for (int n = 0; n < 4; ++n) {
          float v = elu1(acc[m][n][r] + bj[n]);
          rs += v;
          cs[n] += v;
        }
#pragma unroll
        for (int msk = 1; msk < 16; msk <<= 1) rs += __shfl_xor(rs, msk);
        if (fr == 0) {
          int tg = wr * 128 + m * 16 + fq * 4 + r;
          krow[((size_t)bm * NH + head) * T_ + tg] = rs;
        }
      }
    }
#pragma unroll
    for (int n = 0; n < 4; ++n) {
      cs[n] += __shfl_xor(cs[n], 16);
      cs[n] += __shfl_xor(cs[n], 32);
      if (fq == 0)
        ksum2[((size_t)wr * BM_ + bm) * C_ + tn * 256 + wc * 64 + n * 16 + fr] = cs[n];
    }
  } else {
    float ks[4];
#pragma unroll
    for (int n = 0; n < 4; ++n) {
      size_t col = (size_t)bm * C_ + tn * 256 + wc * 64 + n * 16 + fr;
      ks[n] = ksum2_in[col] + ksum2_in[(size_t)BM_ * C_ + col];
    }
#pragma unroll
    for (int m = 0; m < 8; ++m) {
#pragma unroll
      for (int r = 0; r < 4; ++r) {
        float zs = 0.f;
#pragma unroll
        for (int n = 0; n < 4; ++n) zs = fmaf(elu1(acc[m][n][r] + bj[n]), ks[n], zs);
#pragma unroll
        for (int msk = 1; msk < 16; msk <<= 1) zs += __shfl_xor(zs, msk);
        if (fr == 0) {
          int tg = wr * 128 + m * 16 + fq * 4 + r;
          zden[((size_t)bm * NH + head) * T_ + tg] = zs;
        }
      }
    }
  }
}

// xk4[q][bm,n,c] = sum_{t in quarter q} krow_n[t] * x[bm,t,c]; srow4 likewise.
__global__ __launch_bounds__(256) void xk_kernel(
    const unsigned short* __restrict__ xb, const float* __restrict__ krow,
    float* __restrict__ xk4, float* __restrict__ srow4)
{
  const int bm = blockIdx.x, qt = blockIdx.y, tid = threadIdx.x;
  __shared__ float krs[NH * 64];
#pragma unroll
  for (int p = 0; p < 2; ++p) {
    int idx = tid + p * 256;
    int n = idx >> 6, t = idx & 63;
    krs[idx] = krow[((size_t)bm * NH + n) * T_ + qt * 64 + t];
  }
  __syncthreads();
  float a0[8], a1[8];
#pragma unroll
  for (int n = 0; n < 8; ++n) { a0[n] = 0.f; a1[n] = 0.f; }
  const unsigned short* xp = xb + ((size_t)bm * T_ + qt * 64) * C_ + tid * 2;
  for (int t = 0; t < 64; ++t) {
    ushort2 u = *reinterpret_cast<const ushort2*>(xp + (size_t)t * C_);
    float x0 = bf2f(u.x), x1 = bf2f(u.y);
#pragma unroll
    for (int n = 0; n < 8; ++n) {
      float kr = krs[n * 64 + t];
      a0[n] = fmaf(kr, x0, a0[n]);
      a1[n] = fmaf(kr, x1, a1[n]);
    }
  }
#pragma unroll
  for (int n = 0; n < 8; ++n)
    *reinterpret_cast<float2*>(&xk4[(((size_t)qt * BM_ + bm) * NH + n) * C_ + tid * 2])
        = make_float2(a0[n], a1[n]);
  if (tid < 8) {
    float s = 0.f;
    for (int t = 0; t < 64; ++t) s += krs[tid * 64 + t];
    srow4[((size_t)qt * BM_ + bm) * NH + tid] = s;
  }
}

// colsum[bm,h,e] = Wv[h*64+e,:] . (sum_q xk4) + (sum_q srow4)*bv[h*64+e]
__global__ __launch_bounds__(256) void colsum_kernel(
    const float* __restrict__ xk4, const float* __restrict__ srow4,
    const float* __restrict__ Wv, const float* __restrict__ bv,
    float* __restrict__ cs_g)
{
  const int bm0 = blockIdx.x * 8, h = blockIdx.y, tid = threadIdx.x;
  __shared__ float4 xs4[8][128];
#pragma unroll
  for (int p = 0; p < 4; ++p) {
    int idx = tid + p * 256;
    int bmr = idx >> 7, c4 = idx & 127;
    float4 s = make_float4(0.f, 0.f, 0.f, 0.f);
#pragma unroll
    for (int q = 0; q < 4; ++q) {
      float4 u = *reinterpret_cast<const float4*>(
          xk4 + (((size_t)q * BM_ + bm0 + bmr) * NH + h) * C_ + c4 * 4);
      s.x += u.x; s.y += u.y; s.z += u.z; s.w += u.w;
    }
    xs4[bmr][c4] = s;
  }
  __syncthreads();
  const int e = tid & 63, bs = tid >> 6;
  const float4* wv4 = reinterpret_cast<const float4*>(Wv + (size_t)(h * DH + e) * C_);
  float acc0 = 0.f, acc1 = 0.f;
#pragma unroll 4
  for (int c4 = 0; c4 < 128; ++c4) {
    float4 w = wv4[c4];
    float4 a = xs4[bs * 2][c4];
    float4 b = xs4[bs * 2 + 1][c4];
    acc0 += w.x * a.x + w.y * a.y + w.z * a.z + w.w * a.w;
    acc1 += w.x * b.x + w.y * b.y + w.z * b.z + w.w * b.w;
  }
  float bve = bv[h * DH + e];
  int bmA = bm0 + bs * 2, bmB = bmA + 1;
  float sA = 0.f, sB = 0.f;
#pragma unroll
  for (int q = 0; q < 4; ++q) {
    sA += srow4[((size_t)q * BM_ + bmA) * NH + h];
    sB += srow4[((size_t)q * BM_ + bmB) * NH + h];
  }
  cs_g[((size_t)bmA * NH + h) * DH + e] = acc0 + sA * bve;
  cs_g[((size_t)bmB * NH + h) * DH + e] = acc1 + sB * bve;
}

// wbuf[bm,h,cp] = sum_e cs[bm,h,e] * Wp[cp, h*64+e]
__global__ __launch_bounds__(256) void wbuf_kernel(
    const float* __restrict__ cs_g, const float* __restrict__ Wp,
    float* __restrict__ wbuf)
{
  const int cpt = blockIdx.x, h = blockIdx.y, bm0 = blockIdx.z * 16;
  const int tid = threadIdx.x;
  __shared__ float4 csL4[16][16];
  {
    int bmr = tid >> 4, e4 = tid & 15;
    csL4[bmr][e4] = *reinterpret_cast<const float4*>(
        cs_g + ((size_t)(bm0 + bmr) * NH + h) * DH + e4 * 4);
  }
  __syncthreads();
  const int cp = cpt * 256 + tid;
  float4 wp[16];
  const float4* wpr = reinterpret_cast<const float4*>(Wp + (size_t)cp * C_ + h * DH);
#pragma unroll
  for (int e4 = 0; e4 < 16; ++e4) wp[e4] = wpr[e4];
#pragma unroll
  for (int bmr = 0; bmr < 16; ++bmr) {
    float acc = 0.f;
#pragma unroll
    for (int e4 = 0; e4 < 16; ++e4) {
      float4 c = csL4[bmr][e4];
      acc += wp[e4].x * c.x + wp[e4].y * c.y + wp[e4].z * c.z + wp[e4].w * c.w;
    }
    wbuf[((size_t)(bm0 + bmr) * NH + h) * C_ + cp] = acc;
  }
}

// out[bm,t,c'] = sum_n z_n[t]*w_n[c'] + bp[c'],  z = 1/(zden+eps)
__global__ __launch_bounds__(256) void out_kernel(
    const float* __restrict__ zden, const float* __restrict__ wbuf,
    const float* __restrict__ bp, float* __restrict__ out)
{
  const int bm = blockIdx.x, tt = blockIdx.y, tid = threadIdx.x;
  __shared__ float zs[NH][64];
#pragma unroll
  for (int p = 0; p < 2; ++p) {
    int idx = tid + p * 256;
    int n = idx >> 6, t = idx & 63;
    zs[n][t] = 1.f / (zden[((size_t)bm * NH + n) * T_ + tt * 64 + t] + 1e-6f);
  }
  float2 wv[8];
  const int c2 = tid * 2;
#pragma unroll
  for (int n = 0; n < 8; ++n)
    wv[n] = *reinterpret_cast<const float2*>(wbuf + ((size_t)bm * NH + n) * C_ + c2);
  float2 bpv = *reinterpret_cast<const float2*>(bp + c2);
  __syncthreads();
  float* ob = out + ((size_t)bm * T_ + tt * 64) * C_;
  for (int t = 0; t < 64; ++t) {
    float o0 = bpv.x, o1 = bpv.y;
#pragma unroll
    for (int n = 0; n < 8; ++n) { float z = zs[n][t]; o0 = fmaf(z, wv[n].x, o0); o1 = fmaf(z, wv[n].y, o1); }
    *reinterpret_cast<float2*>(ob + (size_t)t * C_ + c2) = make_float2(o0, o1);
  }
}

extern "C" void kernel_launch(void* const* d_in, const int* in_sizes, int n_in,
                              void* d_out, int out_size, void* d_ws, size_t ws_size,
                              hipStream_t stream)
{
  const float* x  = (const float*)d_in[0];
  const float* Wq = (const float*)d_in[1];
  const float* bq = (const float*)d_in[2];
  const float* Wk = (const float*)d_in[3];
  const float* bk = (const float*)d_in[4];
  const float* Wv = (const float*)d_in[5];
  const float* bv = (const float*)d_in[6];
  const float* Wp = (const float*)d_in[7];
  const float* bp = (const float*)d_in[8];
  float* out = (float*)d_out;

  float* ws    = (float*)d_ws;
  float* zden  = ws;                        // 262144 f
  float* ksum2 = zden + 262144;             // 131072 f
  float* krow  = ksum2 + 131072;            // 262144 f
  float* srow4 = krow + 262144;             // 4096 f
  float* xk4   = srow4 + 4096;              // 2097152 f
  float* cs    = xk4 + 2097152;             // 65536 f
  float* wbuf  = cs + 65536;                // 524288 f
  unsigned short* xb  = (unsigned short*)(wbuf + 524288);  // 16.7M bf16
  unsigned short* wkb = xb + 16777216;
  unsigned short* wqb = wkb + 262144;

  wcvt_kernel<<<256, 256, 0, stream>>>(Wk, Wq, wkb, wqb);

  gemm_proj<0><<<256, 512, 0, stream>>>(nullptr, x, xb, (const bf16*)wkb, bk,
                                        krow, ksum2, nullptr, nullptr);
  xk_kernel<<<dim3(BM_, 4), 256, 0, stream>>>(xb, krow, xk4, srow4);
  colsum_kernel<<<dim3(16, 8), 256, 0, stream>>>(xk4, srow4, Wv, bv, cs);
  wbuf_kernel<<<dim3(2, 8, 8), 256, 0, stream>>>(cs, Wp, wbuf);
  gemm_proj<1><<<256, 512, 0, stream>>>((const bf16*)xb, nullptr, nullptr,
                                        (const bf16*)wqb, bq,
                                        nullptr, ksum2, ksum2, zden);
  out_kernel<<<dim3(BM_, 4), 256, 0, stream>>>(zden, wbuf, bp, out);
}